// Round 18
// baseline (770.864 us; speedup 1.0000x reference)
//
#include <hip/hip_runtime.h>

typedef __attribute__((ext_vector_type(4))) int i32x4;
typedef __attribute__((ext_vector_type(8))) short bf16x8;
typedef __attribute__((ext_vector_type(4))) float f32x4;
typedef __attribute__((ext_vector_type(8))) unsigned short u16x8;
typedef __attribute__((ext_vector_type(8))) char c8x8;

#define BAR() __builtin_amdgcn_s_barrier()
#define VMC(n) asm volatile("s_waitcnt vmcnt(" #n ")" ::: "memory")
#define SB0() __builtin_amdgcn_sched_barrier(0)
#define WAITL() do { asm volatile("s_waitcnt lgkmcnt(0)"); SB0(); } while (0)
#define DSRI(dst, base, imm) \
  asm volatile("ds_read_b128 %0, %1 offset:%2" : "=&v"(dst) : "v"(base), "i"(imm))

__device__ inline unsigned short f2bf(float f) {
  unsigned int u = __float_as_uint(f);
  u += 0x7fffu + ((u >> 16) & 1u);
  return (unsigned short)(u >> 16);
}

__device__ inline char q8(float v, float s) {  // s = 127/range
  int q = __float2int_rn(v * s);
  q = q < -127 ? -127 : (q > 127 ? 127 : q);
  return (char)q;
}

__device__ inline void gload_lds16(const void* g, void* l) {
  __builtin_amdgcn_global_load_lds(
      (const __attribute__((address_space(1))) void*)g,
      (__attribute__((address_space(3))) void*)l, 16, 0, 0);
}

// -------- per-tensor weight absmax (atomicMax on float bits) ---------------
__global__ void wabsmax(const float* __restrict__ a, const float* __restrict__ b,
                        const float* __restrict__ c, const float* __restrict__ d,
                        unsigned* __restrict__ sc) {
  int blk = blockIdx.x;
  const float* W;
  int seg;
  size_t base;
  if (blk < 768) { W = a; seg = 0; base = (size_t)blk * 1024; }
  else if (blk < 1024) { W = b; seg = 1; base = (size_t)(blk - 768) * 1024; }
  else if (blk < 2048) { W = c; seg = 2; base = (size_t)(blk - 1024) * 1024; }
  else { W = d; seg = 3; base = (size_t)(blk - 2048) * 1024; }
  float m = 0.0f;
  #pragma unroll
  for (int i = 0; i < 4; ++i)
    m = fmaxf(m, fabsf(W[base + threadIdx.x * 4 + i]));
  #pragma unroll
  for (int o = 32; o; o >>= 1) m = fmaxf(m, __shfl_xor(m, o));
  if ((threadIdx.x & 63) == 0) atomicMax(&sc[seg], __float_as_uint(m));
}

// ------- merged weight transpose + i8 quant: W[K][N] -> Wt[N][K] i8 ---------
__global__ void wtrans_all(const float* __restrict__ qkv_w,
                           const float* __restrict__ proj_w,
                           const float* __restrict__ w1,
                           const float* __restrict__ w2,
                           char* __restrict__ WqT, char* __restrict__ WpT,
                           char* __restrict__ W1T, char* __restrict__ W2T,
                           const unsigned* __restrict__ sc) {
  int idx = blockIdx.x * 256 + threadIdx.x;
  const float* W;
  char* Wt;
  int K, N, seg;
  if (idx < 786432) {
    W = qkv_w; Wt = WqT; K = 512; N = 1536; seg = 0;
  } else if (idx < 1048576) {
    idx -= 786432; W = proj_w; Wt = WpT; K = 512; N = 512; seg = 1;
  } else if (idx < 2097152) {
    idx -= 1048576; W = w1; Wt = W1T; K = 512; N = 2048; seg = 2;
  } else {
    idx -= 2097152; W = w2; Wt = W2T; K = 2048; N = 512; seg = 3;
  }
  float wabs = __uint_as_float(sc[seg]);
  int k = idx / N, n = idx - k * N;
  Wt[(size_t)n * K + k] = q8(W[idx], 127.0f / wabs);
}

// -------- LayerNorm (+ optional shift/window gather), f32 -> i8 (range ±6) --
template <int MODE>
__global__ void ln_k(const float* __restrict__ x, const float* __restrict__ sc,
                     const float* __restrict__ bi, char* __restrict__ o) {
  int t = blockIdx.x * 4 + (threadIdx.x >> 6);
  int l = threadIdx.x & 63;
  size_t src;
  if (MODE == 0) {
    int b = t / 28800, r = t - b * 28800;
    int win = r / 144, tok = r - win * 144;
    int c1 = win / 100, rem = win - c1 * 100;
    int h1 = rem / 10, w1 = rem - h1 * 10;
    int tc = tok / 72, tr = tok - tc * 72;
    int th = tr / 12, tw = tr - th * 12;
    int cs = c1 * 2 + tc, hs = h1 * 6 + th, wsp = w1 * 12 + tw;
    int co = (cs + 1) & 3;
    int ho = hs + 3; if (ho >= 60) ho -= 60;
    int wo = wsp + 6; if (wo >= 120) wo -= 120;
    src = ((size_t)b * 28800 + (co * 60 + ho) * 120 + wo) * 512;
  } else {
    src = (size_t)t * 512;
  }
  const float4* xr = (const float4*)(x + src);
  float4 v0 = xr[l * 2], v1 = xr[l * 2 + 1];
  float s = v0.x + v0.y + v0.z + v0.w + v1.x + v1.y + v1.z + v1.w;
  float s2 = v0.x * v0.x + v0.y * v0.y + v0.z * v0.z + v0.w * v0.w +
             v1.x * v1.x + v1.y * v1.y + v1.z * v1.z + v1.w * v1.w;
  #pragma unroll
  for (int o2 = 32; o2; o2 >>= 1) {
    s += __shfl_xor(s, o2);
    s2 += __shfl_xor(s2, o2);
  }
  float mean = s * (1.0f / 512.0f);
  float var = s2 * (1.0f / 512.0f) - mean * mean;
  float inv = rsqrtf(var + 1e-6f);
  const float4* scp = (const float4*)sc;
  const float4* bip = (const float4*)bi;
  float4 sa = scp[l * 2], sb = scp[l * 2 + 1];
  float4 ba = bip[l * 2], bb = bip[l * 2 + 1];
  const float QS = 127.0f / 6.0f;
  c8x8 ov;
  ov[0] = q8((v0.x - mean) * inv * sa.x + ba.x, QS);
  ov[1] = q8((v0.y - mean) * inv * sa.y + ba.y, QS);
  ov[2] = q8((v0.z - mean) * inv * sa.z + ba.z, QS);
  ov[3] = q8((v0.w - mean) * inv * sa.w + ba.w, QS);
  ov[4] = q8((v1.x - mean) * inv * sb.x + bb.x, QS);
  ov[5] = q8((v1.y - mean) * inv * sb.y + bb.y, QS);
  ov[6] = q8((v1.z - mean) * inv * sb.z + bb.z, QS);
  ov[7] = q8((v1.w - mean) * inv * sb.w + bb.w, QS);
  *(c8x8*)&o[(size_t)t * 512 + l * 8] = ov;
}

// ---- 128x256 i8 MFMA GEMM (mfma_i32_16x16x64_i8), 3-slot ring --------------
template <int EPI>
__launch_bounds__(256, 2)
__global__ void gemmQ(const char* __restrict__ A, const char* __restrict__ Bt,
                      const float* __restrict__ bias, void* __restrict__ outp,
                      const float* __restrict__ res,
                      const unsigned* __restrict__ scu, int widx, float ascale,
                      int M, int N, int K) {
  __shared__ __attribute__((aligned(16))) char lds3[3][24576];
  const int tid = threadIdx.x;
  const int w = tid >> 6, l = tid & 63;
  const int lane15 = l & 15;
  const int ntile = N >> 8;
  const int nwg = gridDim.x;
  const int q = nwg >> 3, r = nwg & 7;
  const int xcd = blockIdx.x & 7, idx8 = blockIdx.x >> 3;
  const int wgid = (xcd < r ? xcd * (q + 1) : r * (q + 1) + (xcd - r) * q) + idx8;
  const int bm = wgid / ntile, bn = wgid - bm * ntile;
  const int KT = K >> 6;

  const int rA0 = w * 16 + (l >> 2);
  const int rA1 = (4 + w) * 16 + (l >> 2);
  const int colx0 = ((l & 3) << 4) ^ (((rA0 >> 1) & 3) << 4);
  const int offA0 = rA0 * K + colx0;
  const int offA1 = rA1 * K + colx0;
  int offB[4];
  #pragma unroll
  for (int j = 0; j < 4; ++j) {
    int rb = (j * 4 + w) * 16 + (l >> 2);
    offB[j] = rb * K + (((l & 3) << 4) ^ (((rb >> 1) & 3) << 4));
  }

  unsigned lds0 = (unsigned)(unsigned long long)
      (__attribute__((address_space(3))) void*)(void*)&lds3[0][0];
  const unsigned comA =
      (unsigned)(lane15 * 64 + (((l >> 4) << 4) ^ (((lane15 >> 1) & 3) << 4)));
  unsigned bA0 = lds0 + comA;
  unsigned bA1 = bA0 + 24576u, bA2 = bA0 + 49152u;
  const unsigned bOffB = 8192u + ((unsigned)w << 12);
  unsigned bB0 = bA0 + bOffB, bB1 = bA1 + bOffB, bB2 = bA2 + bOffB;

  char* p0 = &lds3[0][0];
  char* p1 = &lds3[1][0];
  char* p2 = &lds3[2][0];

  const char* gA = A + (size_t)bm * 128 * K;
  const char* gB = Bt + (size_t)bn * 256 * K;

  i32x4 acc[8][4] = {};
  i32x4 afL[4], afH[4], bfr[4];

  auto STAGE = [&](char* pS, const char* ga, const char* gb) {
    gload_lds16(ga + offA0, pS + w * 1024);
    gload_lds16(ga + offA1, pS + 4096 + w * 1024);
    #pragma unroll
    for (int j = 0; j < 4; ++j)
      gload_lds16(gb + offB[j], pS + 8192 + (j * 4 + w) * 1024);
  };

  STAGE(p0, gA, gB); gA += 64; gB += 64;
  STAGE(p1, gA, gB); gA += 64; gB += 64;
  VMC(6);
  BAR();

  for (int t = 0; t < KT; ++t) {
    if (t < KT - 2) {
      STAGE(p2, gA, gB);
      gA += 64; gB += 64;
    }
    DSRI(afL[0], bA0, 0);    DSRI(afL[1], bA0, 1024);
    DSRI(afL[2], bA0, 2048); DSRI(afL[3], bA0, 3072);
    DSRI(bfr[0], bB0, 0);    DSRI(bfr[1], bB0, 1024);
    DSRI(bfr[2], bB0, 2048); DSRI(bfr[3], bB0, 3072);
    WAITL();
    DSRI(afH[0], bA0, 4096); DSRI(afH[1], bA0, 5120);
    DSRI(afH[2], bA0, 6144); DSRI(afH[3], bA0, 7168);
    SB0();
    __builtin_amdgcn_s_setprio(1);
    #pragma unroll
    for (int mf = 0; mf < 4; ++mf)
      #pragma unroll
      for (int nf = 0; nf < 4; ++nf)
        acc[mf][nf] = __builtin_amdgcn_mfma_i32_16x16x64_i8(
            afL[mf], bfr[nf], acc[mf][nf], 0, 0, 0);
    __builtin_amdgcn_s_setprio(0);
    WAITL();
    __builtin_amdgcn_s_setprio(1);
    #pragma unroll
    for (int mf = 0; mf < 4; ++mf)
      #pragma unroll
      for (int nf = 0; nf < 4; ++nf)
        acc[4 + mf][nf] = __builtin_amdgcn_mfma_i32_16x16x64_i8(
            afH[mf], bfr[nf], acc[4 + mf][nf], 0, 0, 0);
    __builtin_amdgcn_s_setprio(0);
    if (t < KT - 2) { VMC(6); } else if (t == KT - 2) { VMC(0); }
    if (t < KT - 1) BAR();
    unsigned ta = bA0; bA0 = bA1; bA1 = bA2; bA2 = ta;
    unsigned tb = bB0; bB0 = bB1; bB1 = bB2; bB2 = tb;
    char* tp = p0; p0 = p1; p1 = p2; p2 = tp;
  }

  // ---------------- epilogue (dequant + fused ops) ----------------
  const float wabs = __uint_as_float(scu[widx]);
  const float fs = ascale * wabs * (1.0f / 127.0f);
  float* outf = (float*)outp;
  unsigned short* outh = (unsigned short*)outp;
  char* outc = (char*)outp;
  #pragma unroll
  for (int mi = 0; mi < 8; ++mi) {
    #pragma unroll
    for (int j = 0; j < 4; ++j) {
      int grow = bm * 128 + mi * 16 + ((l >> 4) << 2) + j;
      int win = 0, tok = 0;
      size_t rowbase = 0;
      if constexpr (EPI == 0) {
        win = grow / 144;
        tok = grow - win * 144;
      } else if constexpr (EPI == 1) {
        win = grow / 144;
        tok = grow - win * 144;
        int b = win / 200, wl = win - b * 200;
        int c1 = wl / 100, rem = wl - c1 * 100;
        int h1 = rem / 10, w1 = rem - h1 * 10;
        int tc = tok / 72, tr = tok - tc * 72;
        int th = tr / 12, tw = tr - th * 12;
        int cs = c1 * 2 + tc, hs = h1 * 6 + th, wsp = w1 * 12 + tw;
        int co = (cs + 1) & 3;
        int ho = hs + 3; if (ho >= 60) ho -= 60;
        int wo = wsp + 6; if (wo >= 120) wo -= 120;
        rowbase = ((size_t)b * 28800 + (co * 60 + ho) * 120 + wo) * 512;
      }
      #pragma unroll
      for (int nf = 0; nf < 4; ++nf) {
        int gcol = bn * 256 + w * 64 + nf * 16 + lane15;
        float val = (float)acc[mi][nf][j] * fs + bias[gcol];
        if constexpr (EPI == 0) {
          int which = gcol >> 9, hd = (gcol >> 6) & 7, dh = gcol & 63;
          outh[(((size_t)(win * 3 + which) * 8 + hd) * 144 + tok) * 64 + dh] = f2bf(val);
        } else if constexpr (EPI == 1) {
          size_t oi = rowbase + gcol;
          outf[oi] = res[oi] + val;
        } else if constexpr (EPI == 2) {
          float u = 0.7978845608f * (val + 0.044715f * val * val * val);
          float g = val / (1.0f + __expf(-2.0f * u));
          outc[(size_t)grow * N + gcol] = q8(g, 127.0f / 2.75f);
        } else {
          size_t oi = (size_t)grow * N + gcol;
          outf[oi] += val;
        }
      }
    }
  }
}

// ---------------- attention (bf16 compute, i8 output range ±4) --------------
__launch_bounds__(576)
__global__ void attn_k(const unsigned short* __restrict__ qkv,
                       char* __restrict__ owin) {
  __shared__ __attribute__((aligned(16))) unsigned short Ks[144 * 72];
  __shared__ __attribute__((aligned(16))) unsigned short Vt[64 * 168];
  __shared__ __attribute__((aligned(16))) unsigned short Ps[144 * 168];
  __shared__ unsigned char gid[144];
  int bid = blockIdx.x;
  int win = bid >> 3, head = bid & 7;
  const unsigned short* qb = qkv + ((size_t)(win * 3 + 0) * 8 + head) * (144 * 64);
  const unsigned short* kb = qkv + ((size_t)(win * 3 + 1) * 8 + head) * (144 * 64);
  const unsigned short* vb = qkv + ((size_t)(win * 3 + 2) * 8 + head) * (144 * 64);
  int tid = threadIdx.x;
  int wv = tid >> 6, l = tid & 63;
  int lane15 = l & 15, lk = (l >> 4) << 3;
  bf16x8 aq0 = *(const bf16x8*)(qb + (wv * 16 + lane15) * 64 + lk);
  bf16x8 aq1 = *(const bf16x8*)(qb + (wv * 16 + lane15) * 64 + 32 + lk);
  {
    int row = tid >> 2, c0 = (tid & 3) << 4;
    u16x8 ka = *(const u16x8*)(kb + row * 64 + c0);
    u16x8 kc = *(const u16x8*)(kb + row * 64 + c0 + 8);
    *(u16x8*)&Ks[row * 72 + c0] = ka;
    *(u16x8*)&Ks[row * 72 + c0 + 8] = kc;
    u16x8 va = *(const u16x8*)(vb + row * 64 + c0);
    u16x8 vc = *(const u16x8*)(vb + row * 64 + c0 + 8);
    #pragma unroll
    for (int j = 0; j < 8; ++j) Vt[(c0 + j) * 168 + row] = va[j];
    #pragma unroll
    for (int j = 0; j < 8; ++j) Vt[(c0 + 8 + j) * 168 + row] = vc[j];
  }
  for (int i = tid; i < 64 * 24; i += 576) {
    int d = i / 24, m = i - d * 24;
    Vt[d * 168 + 144 + m] = 0;
  }
  for (int i = tid; i < 144 * 24; i += 576) {
    int r = i / 24, c = i - r * 24;
    Ps[r * 168 + 144 + c] = 0;
  }
  if (tid < 144) {
    int wl = win % 200;
    int c1 = wl / 100, rem = wl - c1 * 100;
    int h1 = rem / 10, w1 = rem - h1 * 10;
    int tc = tid / 72, tr = tid - tc * 72;
    int th = tr / 12, tw = tr - th * 12;
    int cs = c1 * 2 + tc, hs = h1 * 6 + th, wsp = w1 * 12 + tw;
    int rc = cs < 2 ? 0 : (cs < 3 ? 1 : 2);
    int rh = hs < 54 ? 0 : (hs < 57 ? 1 : 2);
    int rw = wsp < 108 ? 0 : (wsp < 114 ? 1 : 2);
    if (rw == 1) rw = 2;
    gid[tid] = (unsigned char)(rc * 9 + rh * 3 + rw);
  }
  __syncthreads();
  f32x4 sf[9];
  #pragma unroll
  for (int ct = 0; ct < 9; ++ct) {
    f32x4 z = {};
    bf16x8 b0 = *(const bf16x8*)&Ks[(ct * 16 + lane15) * 72 + lk];
    bf16x8 b1 = *(const bf16x8*)&Ks[(ct * 16 + lane15) * 72 + 32 + lk];
    z = __builtin_amdgcn_mfma_f32_16x16x32_bf16(aq0, b0, z, 0, 0, 0);
    z = __builtin_amdgcn_mfma_f32_16x16x32_bf16(aq1, b1, z, 0, 0, 0);
    sf[ct] = z;
  }
  int gi[4];
  #pragma unroll
  for (int j = 0; j < 4; ++j) gi[j] = gid[wv * 16 + ((l >> 4) << 2) + j];
  float mx[4] = {-1e30f, -1e30f, -1e30f, -1e30f};
  #pragma unroll
  for (int ct = 0; ct < 9; ++ct) {
    int gj = gid[ct * 16 + lane15];
    #pragma unroll
    for (int j = 0; j < 4; ++j) {
      float s = sf[ct][j] * 0.125f;
      if (gj != gi[j]) s = -1e30f;
      sf[ct][j] = s;
      mx[j] = fmaxf(mx[j], s);
    }
  }
  #pragma unroll
  for (int o2 = 8; o2; o2 >>= 1)
    #pragma unroll
    for (int j = 0; j < 4; ++j) mx[j] = fmaxf(mx[j], __shfl_xor(mx[j], o2));
  float sm[4] = {0.f, 0.f, 0.f, 0.f};
  #pragma unroll
  for (int ct = 0; ct < 9; ++ct)
    #pragma unroll
    for (int j = 0; j < 4; ++j) {
      float e = __expf(sf[ct][j] - mx[j]);
      sf[ct][j] = e;
      sm[j] += e;
    }
  #pragma unroll
  for (int o2 = 8; o2; o2 >>= 1)
    #pragma unroll
    for (int j = 0; j < 4; ++j) sm[j] += __shfl_xor(sm[j], o2);
  float rs[4];
  #pragma unroll
  for (int j = 0; j < 4; ++j) rs[j] = 1.0f / sm[j];
  #pragma unroll
  for (int ct = 0; ct < 9; ++ct)
    #pragma unroll
    for (int j = 0; j < 4; ++j)
      Ps[(wv * 16 + ((l >> 4) << 2) + j) * 168 + ct * 16 + lane15] =
          f2bf(sf[ct][j] * rs[j]);
  __syncthreads();
  f32x4 of[4] = {};
  #pragma unroll
  for (int ks = 0; ks < 5; ++ks) {
    bf16x8 ap = *(const bf16x8*)&Ps[(wv * 16 + lane15) * 168 + ks * 32 + lk];
    #pragma unroll
    for (int nt = 0; nt < 4; ++nt) {
      bf16x8 bv = *(const bf16x8*)&Vt[(nt * 16 + lane15) * 168 + ks * 32 + lk];
      of[nt] = __builtin_amdgcn_mfma_f32_16x16x32_bf16(ap, bv, of[nt], 0, 0, 0);
    }
  }
  char* ob = owin + (size_t)win * 144 * 512 + head * 64;
  const float OS = 127.0f / 4.0f;
  #pragma unroll
  for (int nt = 0; nt < 4; ++nt)
    #pragma unroll
    for (int j = 0; j < 4; ++j) {
      int row = wv * 16 + ((l >> 4) << 2) + j;
      ob[(size_t)row * 512 + nt * 16 + lane15] = q8(of[nt][j], OS);
    }
}

extern "C" void kernel_launch(void* const* d_in, const int* in_sizes, int n_in,
                              void* d_out, int out_size, void* d_ws, size_t ws_size,
                              hipStream_t stream) {
  const float* x = (const float*)d_in[0];
  const float* qkv_w = (const float*)d_in[1];
  const float* qkv_b = (const float*)d_in[2];
  const float* proj_w = (const float*)d_in[3];
  const float* proj_b = (const float*)d_in[4];
  const float* n1s = (const float*)d_in[5];
  const float* n1b = (const float*)d_in[6];
  const float* n2s = (const float*)d_in[7];
  const float* n2b = (const float*)d_in[8];
  const float* w1 = (const float*)d_in[9];
  const float* b1 = (const float*)d_in[10];
  const float* w2 = (const float*)d_in[11];
  const float* b2 = (const float*)d_in[12];
  float* out = (float*)d_out;
  char* ws = (char*)d_ws;

  char* WqT = ws;                                  // i8 1536x512
  char* WpT = ws + 1572864;                        // i8 512x512
  char* W1T = ws + 2097152;                        // i8 2048x512
  char* W2T = ws + 4194304;                        // i8 512x2048
  unsigned* scu = (unsigned*)(ws + 5242880);       // 4 x f32-bits absmax
  char* hwin = ws + 6291456;                       // i8 57600x512 (LN1/LN2 out)
  unsigned short* qkvb = (unsigned short*)(ws + 65273856);  // bf16 57600x1536
  char* owin = ws + 242221056;                     // i8 57600x512
  char* mid = ws + 65273856;                       // i8 57600x2048 (aliases qkvb)

  hipMemsetAsync(scu, 0, 16, stream);
  wabsmax<<<3072, 256, 0, stream>>>(qkv_w, proj_w, w1, w2, scu);
  wtrans_all<<<12288, 256, 0, stream>>>(qkv_w, proj_w, w1, w2,
                                        WqT, WpT, W1T, W2T, scu);
  ln_k<0><<<14400, 256, 0, stream>>>(x, n1s, n1b, hwin);
  gemmQ<0><<<450 * 6, 256, 0, stream>>>(hwin, WqT, qkv_b, qkvb, nullptr,
                                        scu, 0, 6.0f / 127.0f, 57600, 1536, 512);
  attn_k<<<3200, 576, 0, stream>>>(qkvb, owin);
  gemmQ<1><<<450 * 2, 256, 0, stream>>>(owin, WpT, proj_b, out, x,
                                        scu, 1, 4.0f / 127.0f, 57600, 512, 512);
  ln_k<1><<<14400, 256, 0, stream>>>(out, n2s, n2b, hwin);
  gemmQ<2><<<450 * 8, 256, 0, stream>>>(hwin, W1T, b1, mid, nullptr,
                                        scu, 2, 6.0f / 127.0f, 57600, 2048, 512);
  gemmQ<3><<<450 * 2, 256, 0, stream>>>(mid, W2T, b2, out, nullptr,
                                        scu, 3, 2.75f / 127.0f, 57600, 512, 2048);
}

// Round 19
// 765.912 us; speedup vs baseline: 1.0065x; 1.0065x over previous
//
#include <hip/hip_runtime.h>

typedef __attribute__((ext_vector_type(4))) int i32x4;
typedef __attribute__((ext_vector_type(8))) short bf16x8;
typedef __attribute__((ext_vector_type(4))) float f32x4;
typedef __attribute__((ext_vector_type(8))) unsigned short u16x8;
typedef __attribute__((ext_vector_type(8))) char c8x8;

#define BAR() __builtin_amdgcn_s_barrier()
#define VMC(n) asm volatile("s_waitcnt vmcnt(" #n ")" ::: "memory")
#define SB0() __builtin_amdgcn_sched_barrier(0)
#define WAITL() do { asm volatile("s_waitcnt lgkmcnt(0)"); SB0(); } while (0)
#define DSRI(dst, base, imm) \
  asm volatile("ds_read_b128 %0, %1 offset:%2" : "=&v"(dst) : "v"(base), "i"(imm))

__device__ inline unsigned short f2bf(float f) {
  unsigned int u = __float_as_uint(f);
  u += 0x7fffu + ((u >> 16) & 1u);
  return (unsigned short)(u >> 16);
}

__device__ inline char q8(float v, float s) {  // s = 127/range
  int q = __float2int_rn(v * s);
  q = q < -127 ? -127 : (q > 127 ? 127 : q);
  return (char)q;
}

__device__ inline void gload_lds16(const void* g, void* l) {
  __builtin_amdgcn_global_load_lds(
      (const __attribute__((address_space(1))) void*)g,
      (__attribute__((address_space(3))) void*)l, 16, 0, 0);
}

// -------- per-tensor weight absmax (atomicMax on float bits) ---------------
__global__ void wabsmax(const float* __restrict__ a, const float* __restrict__ b,
                        const float* __restrict__ c, const float* __restrict__ d,
                        unsigned* __restrict__ sc) {
  int blk = blockIdx.x;
  const float* W;
  int seg;
  size_t base;
  if (blk < 768) { W = a; seg = 0; base = (size_t)blk * 1024; }
  else if (blk < 1024) { W = b; seg = 1; base = (size_t)(blk - 768) * 1024; }
  else if (blk < 2048) { W = c; seg = 2; base = (size_t)(blk - 1024) * 1024; }
  else { W = d; seg = 3; base = (size_t)(blk - 2048) * 1024; }
  float m = 0.0f;
  #pragma unroll
  for (int i = 0; i < 4; ++i)
    m = fmaxf(m, fabsf(W[base + threadIdx.x * 4 + i]));
  #pragma unroll
  for (int o = 32; o; o >>= 1) m = fmaxf(m, __shfl_xor(m, o));
  if ((threadIdx.x & 63) == 0) atomicMax(&sc[seg], __float_as_uint(m));
}

// ------- merged weight transpose + i8 quant: W[K][N] -> Wt[N][K] i8 ---------
__global__ void wtrans_all(const float* __restrict__ qkv_w,
                           const float* __restrict__ proj_w,
                           const float* __restrict__ w1,
                           const float* __restrict__ w2,
                           char* __restrict__ WqT, char* __restrict__ WpT,
                           char* __restrict__ W1T, char* __restrict__ W2T,
                           const unsigned* __restrict__ sc) {
  int idx = blockIdx.x * 256 + threadIdx.x;
  const float* W;
  char* Wt;
  int K, N, seg;
  if (idx < 786432) {
    W = qkv_w; Wt = WqT; K = 512; N = 1536; seg = 0;
  } else if (idx < 1048576) {
    idx -= 786432; W = proj_w; Wt = WpT; K = 512; N = 512; seg = 1;
  } else if (idx < 2097152) {
    idx -= 1048576; W = w1; Wt = W1T; K = 512; N = 2048; seg = 2;
  } else {
    idx -= 2097152; W = w2; Wt = W2T; K = 2048; N = 512; seg = 3;
  }
  float wabs = __uint_as_float(sc[seg]);
  int k = idx / N, n = idx - k * N;
  Wt[(size_t)n * K + k] = q8(W[idx], 127.0f / wabs);
}

// -------- LayerNorm (+ optional shift/window gather), f32 -> i8 (range ±6) --
template <int MODE>
__global__ void ln_k(const float* __restrict__ x, const float* __restrict__ sc,
                     const float* __restrict__ bi, char* __restrict__ o) {
  int t = blockIdx.x * 4 + (threadIdx.x >> 6);
  int l = threadIdx.x & 63;
  size_t src;
  if (MODE == 0) {
    int b = t / 28800, r = t - b * 28800;
    int win = r / 144, tok = r - win * 144;
    int c1 = win / 100, rem = win - c1 * 100;
    int h1 = rem / 10, w1 = rem - h1 * 10;
    int tc = tok / 72, tr = tok - tc * 72;
    int th = tr / 12, tw = tr - th * 12;
    int cs = c1 * 2 + tc, hs = h1 * 6 + th, wsp = w1 * 12 + tw;
    int co = (cs + 1) & 3;
    int ho = hs + 3; if (ho >= 60) ho -= 60;
    int wo = wsp + 6; if (wo >= 120) wo -= 120;
    src = ((size_t)b * 28800 + (co * 60 + ho) * 120 + wo) * 512;
  } else {
    src = (size_t)t * 512;
  }
  const float4* xr = (const float4*)(x + src);
  float4 v0 = xr[l * 2], v1 = xr[l * 2 + 1];
  float s = v0.x + v0.y + v0.z + v0.w + v1.x + v1.y + v1.z + v1.w;
  float s2 = v0.x * v0.x + v0.y * v0.y + v0.z * v0.z + v0.w * v0.w +
             v1.x * v1.x + v1.y * v1.y + v1.z * v1.z + v1.w * v1.w;
  #pragma unroll
  for (int o2 = 32; o2; o2 >>= 1) {
    s += __shfl_xor(s, o2);
    s2 += __shfl_xor(s2, o2);
  }
  float mean = s * (1.0f / 512.0f);
  float var = s2 * (1.0f / 512.0f) - mean * mean;
  float inv = rsqrtf(var + 1e-6f);
  const float4* scp = (const float4*)sc;
  const float4* bip = (const float4*)bi;
  float4 sa = scp[l * 2], sb = scp[l * 2 + 1];
  float4 ba = bip[l * 2], bb = bip[l * 2 + 1];
  const float QS = 127.0f / 6.0f;
  c8x8 ov;
  ov[0] = q8((v0.x - mean) * inv * sa.x + ba.x, QS);
  ov[1] = q8((v0.y - mean) * inv * sa.y + ba.y, QS);
  ov[2] = q8((v0.z - mean) * inv * sa.z + ba.z, QS);
  ov[3] = q8((v0.w - mean) * inv * sa.w + ba.w, QS);
  ov[4] = q8((v1.x - mean) * inv * sb.x + bb.x, QS);
  ov[5] = q8((v1.y - mean) * inv * sb.y + bb.y, QS);
  ov[6] = q8((v1.z - mean) * inv * sb.z + bb.z, QS);
  ov[7] = q8((v1.w - mean) * inv * sb.w + bb.w, QS);
  *(c8x8*)&o[(size_t)t * 512 + l * 8] = ov;
}

// ---- 128x256 i8 MFMA GEMM, 2-slot dbuf (48 KiB -> 3 blocks/CU) -------------
// Same tile/swizzle/read structure as the 3-slot ring; prefetch lead = 1
// chunk with VMC(0) drain per chunk, hidden by 3-block cross-desync (m97).
template <int EPI>
__launch_bounds__(256, 2)
__global__ void gemmQ(const char* __restrict__ A, const char* __restrict__ Bt,
                      const float* __restrict__ bias, void* __restrict__ outp,
                      const float* __restrict__ res,
                      const unsigned* __restrict__ scu, int widx, float ascale,
                      int M, int N, int K) {
  __shared__ __attribute__((aligned(16))) char lds2[2][24576];
  const int tid = threadIdx.x;
  const int w = tid >> 6, l = tid & 63;
  const int lane15 = l & 15;
  const int ntile = N >> 8;
  const int nwg = gridDim.x;
  const int q = nwg >> 3, r = nwg & 7;
  const int xcd = blockIdx.x & 7, idx8 = blockIdx.x >> 3;
  const int wgid = (xcd < r ? xcd * (q + 1) : r * (q + 1) + (xcd - r) * q) + idx8;
  const int bm = wgid / ntile, bn = wgid - bm * ntile;
  const int KT = K >> 6;

  const int rA0 = w * 16 + (l >> 2);
  const int rA1 = (4 + w) * 16 + (l >> 2);
  const int colx0 = ((l & 3) << 4) ^ (((rA0 >> 1) & 3) << 4);
  const int offA0 = rA0 * K + colx0;
  const int offA1 = rA1 * K + colx0;
  int offB[4];
  #pragma unroll
  for (int j = 0; j < 4; ++j) {
    int rb = (j * 4 + w) * 16 + (l >> 2);
    offB[j] = rb * K + (((l & 3) << 4) ^ (((rb >> 1) & 3) << 4));
  }

  unsigned lds0 = (unsigned)(unsigned long long)
      (__attribute__((address_space(3))) void*)(void*)&lds2[0][0];
  const unsigned comA =
      (unsigned)(lane15 * 64 + (((l >> 4) << 4) ^ (((lane15 >> 1) & 3) << 4)));
  unsigned bA0 = lds0 + comA;
  unsigned bA1 = bA0 + 24576u;
  const unsigned bOffB = 8192u + ((unsigned)w << 12);
  unsigned bB0 = bA0 + bOffB, bB1 = bA1 + bOffB;

  char* p0 = &lds2[0][0];
  char* p1 = &lds2[1][0];

  const char* gA = A + (size_t)bm * 128 * K;
  const char* gB = Bt + (size_t)bn * 256 * K;

  i32x4 acc[8][4] = {};
  i32x4 afL[4], afH[4], bfr[4];

  auto STAGE = [&](char* pS, const char* ga, const char* gb) {
    gload_lds16(ga + offA0, pS + w * 1024);
    gload_lds16(ga + offA1, pS + 4096 + w * 1024);
    #pragma unroll
    for (int j = 0; j < 4; ++j)
      gload_lds16(gb + offB[j], pS + 8192 + (j * 4 + w) * 1024);
  };

  // prologue: stage chunk 0 only (1-ahead dbuf)
  STAGE(p0, gA, gB); gA += 64; gB += 64;
  VMC(0);
  BAR();

  for (int t = 0; t < KT; ++t) {
    const bool st = (t + 1 < KT);
    if (st) {  // stage next chunk into the other slot
      STAGE(p1, gA, gB);
      gA += 64; gB += 64;
    }
    DSRI(afL[0], bA0, 0);    DSRI(afL[1], bA0, 1024);
    DSRI(afL[2], bA0, 2048); DSRI(afL[3], bA0, 3072);
    DSRI(bfr[0], bB0, 0);    DSRI(bfr[1], bB0, 1024);
    DSRI(bfr[2], bB0, 2048); DSRI(bfr[3], bB0, 3072);
    WAITL();
    DSRI(afH[0], bA0, 4096); DSRI(afH[1], bA0, 5120);
    DSRI(afH[2], bA0, 6144); DSRI(afH[3], bA0, 7168);
    SB0();
    __builtin_amdgcn_s_setprio(1);
    #pragma unroll
    for (int mf = 0; mf < 4; ++mf)
      #pragma unroll
      for (int nf = 0; nf < 4; ++nf)
        acc[mf][nf] = __builtin_amdgcn_mfma_i32_16x16x64_i8(
            afL[mf], bfr[nf], acc[mf][nf], 0, 0, 0);
    __builtin_amdgcn_s_setprio(0);
    WAITL();
    __builtin_amdgcn_s_setprio(1);
    #pragma unroll
    for (int mf = 0; mf < 4; ++mf)
      #pragma unroll
      for (int nf = 0; nf < 4; ++nf)
        acc[4 + mf][nf] = __builtin_amdgcn_mfma_i32_16x16x64_i8(
            afH[mf], bfr[nf], acc[4 + mf][nf], 0, 0, 0);
    __builtin_amdgcn_s_setprio(0);
    if (st) {
      VMC(0);  // next slot fully staged
      BAR();
      unsigned ta = bA0; bA0 = bA1; bA1 = ta;
      unsigned tb = bB0; bB0 = bB1; bB1 = tb;
      char* tp = p0; p0 = p1; p1 = tp;
    }
  }

  // ---------------- epilogue (dequant + fused ops) ----------------
  const float wabs = __uint_as_float(scu[widx]);
  const float fs = ascale * wabs * (1.0f / 127.0f);
  float* outf = (float*)outp;
  unsigned short* outh = (unsigned short*)outp;
  char* outc = (char*)outp;
  #pragma unroll
  for (int mi = 0; mi < 8; ++mi) {
    #pragma unroll
    for (int j = 0; j < 4; ++j) {
      int grow = bm * 128 + mi * 16 + ((l >> 4) << 2) + j;
      int win = 0, tok = 0;
      size_t rowbase = 0;
      if constexpr (EPI == 0) {
        win = grow / 144;
        tok = grow - win * 144;
      } else if constexpr (EPI == 1) {
        win = grow / 144;
        tok = grow - win * 144;
        int b = win / 200, wl = win - b * 200;
        int c1 = wl / 100, rem = wl - c1 * 100;
        int h1 = rem / 10, w1 = rem - h1 * 10;
        int tc = tok / 72, tr = tok - tc * 72;
        int th = tr / 12, tw = tr - th * 12;
        int cs = c1 * 2 + tc, hs = h1 * 6 + th, wsp = w1 * 12 + tw;
        int co = (cs + 1) & 3;
        int ho = hs + 3; if (ho >= 60) ho -= 60;
        int wo = wsp + 6; if (wo >= 120) wo -= 120;
        rowbase = ((size_t)b * 28800 + (co * 60 + ho) * 120 + wo) * 512;
      }
      #pragma unroll
      for (int nf = 0; nf < 4; ++nf) {
        int gcol = bn * 256 + w * 64 + nf * 16 + lane15;
        float val = (float)acc[mi][nf][j] * fs + bias[gcol];
        if constexpr (EPI == 0) {
          int which = gcol >> 9, hd = (gcol >> 6) & 7, dh = gcol & 63;
          outh[(((size_t)(win * 3 + which) * 8 + hd) * 144 + tok) * 64 + dh] = f2bf(val);
        } else if constexpr (EPI == 1) {
          size_t oi = rowbase + gcol;
          outf[oi] = res[oi] + val;
        } else if constexpr (EPI == 2) {
          float u = 0.7978845608f * (val + 0.044715f * val * val * val);
          float g = val / (1.0f + __expf(-2.0f * u));
          outc[(size_t)grow * N + gcol] = q8(g, 127.0f / 2.75f);
        } else {
          size_t oi = (size_t)grow * N + gcol;
          outf[oi] += val;
        }
      }
    }
  }
}

// ---------------- attention (bf16 compute, i8 output range ±4) --------------
__launch_bounds__(576)
__global__ void attn_k(const unsigned short* __restrict__ qkv,
                       char* __restrict__ owin) {
  __shared__ __attribute__((aligned(16))) unsigned short Ks[144 * 72];
  __shared__ __attribute__((aligned(16))) unsigned short Vt[64 * 168];
  __shared__ __attribute__((aligned(16))) unsigned short Ps[144 * 168];
  __shared__ unsigned char gid[144];
  int bid = blockIdx.x;
  int win = bid >> 3, head = bid & 7;
  const unsigned short* qb = qkv + ((size_t)(win * 3 + 0) * 8 + head) * (144 * 64);
  const unsigned short* kb = qkv + ((size_t)(win * 3 + 1) * 8 + head) * (144 * 64);
  const unsigned short* vb = qkv + ((size_t)(win * 3 + 2) * 8 + head) * (144 * 64);
  int tid = threadIdx.x;
  int wv = tid >> 6, l = tid & 63;
  int lane15 = l & 15, lk = (l >> 4) << 3;
  bf16x8 aq0 = *(const bf16x8*)(qb + (wv * 16 + lane15) * 64 + lk);
  bf16x8 aq1 = *(const bf16x8*)(qb + (wv * 16 + lane15) * 64 + 32 + lk);
  {
    int row = tid >> 2, c0 = (tid & 3) << 4;
    u16x8 ka = *(const u16x8*)(kb + row * 64 + c0);
    u16x8 kc = *(const u16x8*)(kb + row * 64 + c0 + 8);
    *(u16x8*)&Ks[row * 72 + c0] = ka;
    *(u16x8*)&Ks[row * 72 + c0 + 8] = kc;
    u16x8 va = *(const u16x8*)(vb + row * 64 + c0);
    u16x8 vc = *(const u16x8*)(vb + row * 64 + c0 + 8);
    #pragma unroll
    for (int j = 0; j < 8; ++j) Vt[(c0 + j) * 168 + row] = va[j];
    #pragma unroll
    for (int j = 0; j < 8; ++j) Vt[(c0 + 8 + j) * 168 + row] = vc[j];
  }
  for (int i = tid; i < 64 * 24; i += 576) {
    int d = i / 24, m = i - d * 24;
    Vt[d * 168 + 144 + m] = 0;
  }
  for (int i = tid; i < 144 * 24; i += 576) {
    int r = i / 24, c = i - r * 24;
    Ps[r * 168 + 144 + c] = 0;
  }
  if (tid < 144) {
    int wl = win % 200;
    int c1 = wl / 100, rem = wl - c1 * 100;
    int h1 = rem / 10, w1 = rem - h1 * 10;
    int tc = tid / 72, tr = tid - tc * 72;
    int th = tr / 12, tw = tr - th * 12;
    int cs = c1 * 2 + tc, hs = h1 * 6 + th, wsp = w1 * 12 + tw;
    int rc = cs < 2 ? 0 : (cs < 3 ? 1 : 2);
    int rh = hs < 54 ? 0 : (hs < 57 ? 1 : 2);
    int rw = wsp < 108 ? 0 : (wsp < 114 ? 1 : 2);
    if (rw == 1) rw = 2;
    gid[tid] = (unsigned char)(rc * 9 + rh * 3 + rw);
  }
  __syncthreads();
  f32x4 sf[9];
  #pragma unroll
  for (int ct = 0; ct < 9; ++ct) {
    f32x4 z = {};
    bf16x8 b0 = *(const bf16x8*)&Ks[(ct * 16 + lane15) * 72 + lk];
    bf16x8 b1 = *(const bf16x8*)&Ks[(ct * 16 + lane15) * 72 + 32 + lk];
    z = __builtin_amdgcn_mfma_f32_16x16x32_bf16(aq0, b0, z, 0, 0, 0);
    z = __builtin_amdgcn_mfma_f32_16x16x32_bf16(aq1, b1, z, 0, 0, 0);
    sf[ct] = z;
  }
  int gi[4];
  #pragma unroll
  for (int j = 0; j < 4; ++j) gi[j] = gid[wv * 16 + ((l >> 4) << 2) + j];
  float mx[4] = {-1e30f, -1e30f, -1e30f, -1e30f};
  #pragma unroll
  for (int ct = 0; ct < 9; ++ct) {
    int gj = gid[ct * 16 + lane15];
    #pragma unroll
    for (int j = 0; j < 4; ++j) {
      float s = sf[ct][j] * 0.125f;
      if (gj != gi[j]) s = -1e30f;
      sf[ct][j] = s;
      mx[j] = fmaxf(mx[j], s);
    }
  }
  #pragma unroll
  for (int o2 = 8; o2; o2 >>= 1)
    #pragma unroll
    for (int j = 0; j < 4; ++j) mx[j] = fmaxf(mx[j], __shfl_xor(mx[j], o2));
  float sm[4] = {0.f, 0.f, 0.f, 0.f};
  #pragma unroll
  for (int ct = 0; ct < 9; ++ct)
    #pragma unroll
    for (int j = 0; j < 4; ++j) {
      float e = __expf(sf[ct][j] - mx[j]);
      sf[ct][j] = e;
      sm[j] += e;
    }
  #pragma unroll
  for (int o2 = 8; o2; o2 >>= 1)
    #pragma unroll
    for (int j = 0; j < 4; ++j) sm[j] += __shfl_xor(sm[j], o2);
  float rs[4];
  #pragma unroll
  for (int j = 0; j < 4; ++j) rs[j] = 1.0f / sm[j];
  #pragma unroll
  for (int ct = 0; ct < 9; ++ct)
    #pragma unroll
    for (int j = 0; j < 4; ++j)
      Ps[(wv * 16 + ((l >> 4) << 2) + j) * 168 + ct * 16 + lane15] =
          f2bf(sf[ct][j] * rs[j]);
  __syncthreads();
  f32x4 of[4] = {};
  #pragma unroll
  for (int ks = 0; ks < 5; ++ks) {
    bf16x8 ap = *(const bf16x8*)&Ps[(wv * 16 + lane15) * 168 + ks * 32 + lk];
    #pragma unroll
    for (int nt = 0; nt < 4; ++nt) {
      bf16x8 bv = *(const bf16x8*)&Vt[(nt * 16 + lane15) * 168 + ks * 32 + lk];
      of[nt] = __builtin_amdgcn_mfma_f32_16x16x32_bf16(ap, bv, of[nt], 0, 0, 0);
    }
  }
  char* ob = owin + (size_t)win * 144 * 512 + head * 64;
  const float OS = 127.0f / 4.0f;
  #pragma unroll
  for (int nt = 0; nt < 4; ++nt)
    #pragma unroll
    for (int j = 0; j < 4; ++j) {
      int row = wv * 16 + ((l >> 4) << 2) + j;
      ob[(size_t)row * 512 + nt * 16 + lane15] = q8(of[nt][j], OS);
    }
}

extern "C" void kernel_launch(void* const* d_in, const int* in_sizes, int n_in,
                              void* d_out, int out_size, void* d_ws, size_t ws_size,
                              hipStream_t stream) {
  const float* x = (const float*)d_in[0];
  const float* qkv_w = (const float*)d_in[1];
  const float* qkv_b = (const float*)d_in[2];
  const float* proj_w = (const float*)d_in[3];
  const float* proj_b = (const float*)d_in[4];
  const float* n1s = (const float*)d_in[5];
  const float* n1b = (const float*)d_in[6];
  const float* n2s = (const float*)d_in[7];
  const float* n2b = (const float*)d_in[8];
  const float* w1 = (const float*)d_in[9];
  const float* b1 = (const float*)d_in[10];
  const float* w2 = (const float*)d_in[11];
  const float* b2 = (const float*)d_in[12];
  float* out = (float*)d_out;
  char* ws = (char*)d_ws;

  char* WqT = ws;                                  // i8 1536x512
  char* WpT = ws + 1572864;                        // i8 512x512
  char* W1T = ws + 2097152;                        // i8 2048x512
  char* W2T = ws + 4194304;                        // i8 512x2048
  unsigned* scu = (unsigned*)(ws + 5242880);       // 4 x f32-bits absmax
  char* hwin = ws + 6291456;                       // i8 57600x512 (LN1/LN2 out)
  unsigned short* qkvb = (unsigned short*)(ws + 65273856);  // bf16 57600x1536
  char* owin = ws + 242221056;                     // i8 57600x512
  char* mid = ws + 65273856;                       // i8 57600x2048 (aliases qkvb)

  hipMemsetAsync(scu, 0, 16, stream);
  wabsmax<<<3072, 256, 0, stream>>>(qkv_w, proj_w, w1, w2, scu);
  wtrans_all<<<12288, 256, 0, stream>>>(qkv_w, proj_w, w1, w2,
                                        WqT, WpT, W1T, W2T, scu);
  ln_k<0><<<14400, 256, 0, stream>>>(x, n1s, n1b, hwin);
  gemmQ<0><<<450 * 6, 256, 0, stream>>>(hwin, WqT, qkv_b, qkvb, nullptr,
                                        scu, 0, 6.0f / 127.0f, 57600, 1536, 512);
  attn_k<<<3200, 576, 0, stream>>>(qkvb, owin);
  gemmQ<1><<<450 * 2, 256, 0, stream>>>(owin, WpT, proj_b, out, x,
                                        scu, 1, 4.0f / 127.0f, 57600, 512, 512);
  ln_k<1><<<14400, 256, 0, stream>>>(out, n2s, n2b, hwin);
  gemmQ<2><<<450 * 8, 256, 0, stream>>>(hwin, W1T, b1, mid, nullptr,
                                        scu, 2, 6.0f / 127.0f, 57600, 2048, 512);
  gemmQ<3><<<450 * 2, 256, 0, stream>>>(mid, W2T, b2, out, nullptr,
                                        scu, 3, 2.75f / 127.0f, 57600, 512, 2048);
}